// Round 13
// baseline (336.836 us; speedup 1.0000x reference)
//
#include <hip/hip_runtime.h>

// ---------------------------------------------------------------------------
// Qwen3-style attention block on MI355X (gfx950), bf16 MFMA pipeline.
// B=2, S=1024, HID=4096, H=32, KV=8, D=128.
// Stages: cvt(h,Wq,Wk,Wv) -> QKV GEMM (+Wo-cvt tail)
//         -> flash attn (Q AND K RMSNorm+RoPE fused) -> out GEMM (gemm2p128).
// v13: QKV phase reads made m201-exact (12,4,8,4 + lgkmcnt(8) throttle);
// rms_rope kernel removed (K-norm+rope fused into attn K-staging with
// identical final LDS layout); GEMM cores otherwise = round-12 (best).
// ---------------------------------------------------------------------------

typedef __attribute__((ext_vector_type(8))) short s8v;            // 8 bf16 (4 VGPR)
typedef __attribute__((ext_vector_type(4))) float f4v;
typedef __attribute__((ext_vector_type(8))) unsigned short u8v;
typedef __attribute__((ext_vector_type(4))) float float4v;
typedef __attribute__((ext_vector_type(2))) float float2v;
typedef unsigned short us;

#define SB() __builtin_amdgcn_sched_barrier(0)

__device__ __forceinline__ void BARRIER() {
  asm volatile("" ::: "memory");
  __builtin_amdgcn_s_barrier();
  asm volatile("" ::: "memory");
}

__device__ __forceinline__ us f2b(float f) {
  unsigned u = __builtin_bit_cast(unsigned, f);
  u += 0x7fffu + ((u >> 16) & 1u);            // round-to-nearest-even
  return (us)(u >> 16);
}
__device__ __forceinline__ float b2f(us h) {
  return __builtin_bit_cast(float, (unsigned)h << 16);
}

__device__ __forceinline__ void gload16(const void* g, void* l) {
  __builtin_amdgcn_global_load_lds(
      (const __attribute__((address_space(1))) unsigned int*)g,
      (__attribute__((address_space(3))) unsigned int*)l, 16, 0, 0);
}

// ---------------------------------------------------------------------------
// Fused f32 -> bf16 convert: hidden|Wq|Wk|Wv, contiguous bf16 destination.
// ---------------------------------------------------------------------------
__global__ __launch_bounds__(256) void cvt_all_k(const float* __restrict__ h,
                                                 const float* __restrict__ wq,
                                                 const float* __restrict__ wk,
                                                 const float* __restrict__ wv,
                                                 us* __restrict__ dst) {
  long blk = blockIdx.x;
  const float* src;
  long off;
  if (blk < 4096)        { src = h;  off = 0; }
  else if (blk < 12288)  { src = wq; off = 4096; }
  else if (blk < 14336)  { src = wk; off = 12288; }
  else                   { src = wv; off = 14336; }
  long i = (blk - off) * 2048 + (long)threadIdx.x * 8;
  long o = blk * 2048 + (long)threadIdx.x * 8;
  float4v a = *(const float4v*)(src + i);
  float4v b = *(const float4v*)(src + i + 4);
  u8v v;
  v[0] = f2b(a[0]); v[1] = f2b(a[1]); v[2] = f2b(a[2]); v[3] = f2b(a[3]);
  v[4] = f2b(b[0]); v[5] = f2b(b[1]); v[6] = f2b(b[2]); v[7] = f2b(b[3]);
  *(u8v*)(dst + o) = v;
}

// ---------------------------------------------------------------------------
// m201-style 8-phase bf16 GEMM (QKV): C[M,N] = A[M,K] * W[N,K]^T
// 256x256 tile, 16x16x32 MFMA, counted vmcnt, chunk-XOR swizzle.
// v13: m201-exact reads (12,4,8,4; lgkmcnt(8) throttle on the 12-read phase).
// ---------------------------------------------------------------------------
template <int AH, bool F32OUT, bool CVTTAIL>
__global__ __launch_bounds__(512, 2) void gemm8p(const us* __restrict__ A,
                                                 const us* __restrict__ W,
                                                 void* __restrict__ Cv,
                                                 int K, int nkt, int ldc,
                                                 int cm, int cn, int ncn,
                                                 int nGemm,
                                                 const float* __restrict__ csrc,
                                                 us* __restrict__ cdst) {
  if constexpr (CVTTAIL) {
    if ((int)blockIdx.x >= nGemm) {
      long c = (long)((int)blockIdx.x - nGemm) * 512 + threadIdx.x;
      for (; c < 2097152; c += 64 * 512) {      // 16,777,216 elems / 8
        long i = c * 8;
        float4v x = *(const float4v*)(csrc + i);
        float4v y = *(const float4v*)(csrc + i + 4);
        u8v v;
        v[0] = f2b(x[0]); v[1] = f2b(x[1]); v[2] = f2b(x[2]); v[3] = f2b(x[3]);
        v[4] = f2b(y[0]); v[5] = f2b(y[1]); v[6] = f2b(y[2]); v[7] = f2b(y[3]);
        *(u8v*)(cdst + i) = v;
      }
      return;
    }
  }

  constexpr int FR = AH / 32;
  constexpr int LA = AH / 64;
  constexpr int VM = 2 * LA + 2;

  __shared__ __align__(16) us Ah[2][2][AH * 64];
  __shared__ __align__(16) us Bh[2][2][128 * 64];
  const int tid = threadIdx.x, lane = tid & 63, w = tid >> 6;
  const int wr = w >> 2, wc = w & 3;
  const int lr = lane & 15, lg = lane >> 4;

  const int xcd = (int)blockIdx.x & 7;
  const int i2 = (int)blockIdx.x >> 3;
  const int im = i2 % cm, itn = i2 / cm;
  const long m0 = (long)((xcd / ncn) * cm + im) * (2 * AH);
  const long n0 = (long)((xcd % ncn) * cn + itn) * 256;

  const int rA0 = tid >> 3;
  const int sc0 = ((tid & 7) ^ (rA0 & 7)) << 3;

#define STGH(dst, src, LOADS)                                           \
  do {                                                                  \
    const us* _s = (src);                                               \
    us* _d = (dst);                                                     \
    _Pragma("unroll") for (int l = 0; l < (LOADS); ++l)                 \
      gload16(_s + (long)(rA0 + l * 64) * K + sc0, _d + (l * 512 + tid) * 8); \
  } while (0)

  const us* Asrc = A + m0 * K;
  const us* Bsrc = W + n0 * K;
  const long hKA = (long)AH * K;
  const long hKB = (long)128 * K;

  const int ra = wr * (AH / 2) + lr, rb = wc * 32 + lr;
  const int offA0 = ra * 64 + ((lg ^ (ra & 7)) << 3);
  const int offA1 = ra * 64 + (((4 + lg) ^ (ra & 7)) << 3);
  const int offB0 = rb * 64 + ((lg ^ (rb & 7)) << 3);
  const int offB1 = rb * 64 + (((4 + lg) ^ (rb & 7)) << 3);

  f4v acc[2 * FR][4];
#pragma unroll
  for (int i = 0; i < 2 * FR; ++i)
#pragma unroll
    for (int j = 0; j < 4; ++j) acc[i][j] = (f4v){0.f, 0.f, 0.f, 0.f};

  const int nk = nkt;

  STGH(Ah[0][0], Asrc, LA);
  STGH(Bh[0][0], Bsrc, 2);
  STGH(Bh[0][1], Bsrc + hKB, 2);
  STGH(Ah[0][1], Asrc + hKA, LA);
  STGH(Ah[1][0], Asrc + 64, LA);
  STGH(Bh[1][1], Bsrc + hKB + 64, 2);
  STGH(Ah[1][1], Asrc + hKA + 64, LA);
  asm volatile("s_waitcnt vmcnt(%0)" :: "i"(VM) : "memory");
  BARRIER();

  s8v a[FR][2], b0[2][2], b1[2][2];

#define RD_A(H)                                                         \
  _Pragma("unroll") for (int f = 0; f < FR; ++f) {                      \
    a[f][0] = *(const s8v*)(&Ah[d][H][offA0 + f * 1024]);               \
    a[f][1] = *(const s8v*)(&Ah[d][H][offA1 + f * 1024]);               \
  }
#define RD_B(BB, H)                                                     \
  _Pragma("unroll") for (int g = 0; g < 2; ++g) {                       \
    BB[g][0] = *(const s8v*)(&Bh[d][H][offB0 + g * 1024]);              \
    BB[g][1] = *(const s8v*)(&Bh[d][H][offB1 + g * 1024]);              \
  }
#define QUAD(QM, QN, BB)                                                \
  __builtin_amdgcn_s_setprio(1);                                        \
  _Pragma("unroll") for (int f = 0; f < FR; ++f)                        \
  _Pragma("unroll") for (int g = 0; g < 2; ++g) {                       \
    f4v t = acc[QM * FR + f][QN * 2 + g];                               \
    t = __builtin_amdgcn_mfma_f32_16x16x32_bf16(a[f][0], BB[g][0], t, 0, 0, 0); \
    t = __builtin_amdgcn_mfma_f32_16x16x32_bf16(a[f][1], BB[g][1], t, 0, 0, 0); \
    acc[QM * FR + f][QN * 2 + g] = t;                                   \
  }                                                                     \
  __builtin_amdgcn_s_setprio(0);
#define PREMFMA()                                                       \
  BARRIER();                                                            \
  asm volatile("s_waitcnt lgkmcnt(0)" ::: "memory");                    \
  SB();

  for (int kt = 0; kt < nk; ++kt) {
    const int d = kt & 1;
    const long kb2 = (long)(kt + 2) * 64;
    const bool p1 = (kt + 1 < nk), p2 = (kt + 2 < nk);

    // ---- phase 1: q(0,0); 12 reads; stage B0(kt+1); lgkm throttle ----
    RD_A(0)
    RD_B(b0, 0)
    if (p1) STGH(Bh[d ^ 1][0], Bsrc + (long)(kt + 1) * 64, 2);
    asm volatile("s_waitcnt lgkmcnt(8)" ::: "memory");
    PREMFMA()
    QUAD(0, 0, b0)
    BARRIER();

    // ---- phase 2: q(0,1); 4 reads; stage A0(kt+2) ----
    RD_B(b1, 1)
    if (p2) STGH(Ah[d][0], Asrc + kb2, LA);
    PREMFMA()
    QUAD(0, 1, b1)
    BARRIER();

    // ---- phase 3: q(1,1); 8 reads; stage B1(kt+2) ----
    RD_A(1)
    if (p2) STGH(Bh[d][1], Bsrc + hKB + kb2, 2);
    PREMFMA()
    QUAD(1, 1, b1)
    BARRIER();

    // ---- phase 4: q(1,0); 4 reads (B0 re-read, m201-exact); stage A1 ----
    RD_B(b0, 0)
    if (p2) STGH(Ah[d][1], Asrc + hKA + kb2, LA);
    PREMFMA()
    QUAD(1, 0, b0)
    if (p2) asm volatile("s_waitcnt vmcnt(%0)" :: "i"(VM) : "memory");
    else    asm volatile("s_waitcnt vmcnt(0)" ::: "memory");
    BARRIER();
  }

#pragma unroll
  for (int qm = 0; qm < 2; ++qm)
#pragma unroll
    for (int f = 0; f < FR; ++f) {
      long row = m0 + qm * AH + wr * (AH / 2) + f * 16 + lg * 4;
#pragma unroll
      for (int qn = 0; qn < 2; ++qn)
#pragma unroll
        for (int g = 0; g < 2; ++g) {
          long col = n0 + qn * 128 + wc * 32 + g * 16 + lr;
          f4v v = acc[qm * FR + f][qn * 2 + g];
          if constexpr (F32OUT) {
            float* C = (float*)Cv;
#pragma unroll
            for (int r = 0; r < 4; ++r) C[(row + r) * ldc + col] = v[r];
          } else {
            us* C = (us*)Cv;
#pragma unroll
            for (int r = 0; r < 4; ++r) C[(row + r) * ldc + col] = f2b(v[r]);
          }
        }
    }
#undef STGH
#undef RD_A
#undef RD_B
#undef QUAD
#undef PREMFMA
}

// ---------------------------------------------------------------------------
// gemm2p128 (out-proj): C[2048,4096] f32 = A[2048,K]bf16 * W[4096,K]^T
// (round-10/12 core: 128x128 tile, 4 waves, 16x16x32 MFMA, 2 blocks/CU)
// ---------------------------------------------------------------------------
__global__ __launch_bounds__(256, 2) void gemm2p128(const us* __restrict__ A,
                                                    const us* __restrict__ W,
                                                    float* __restrict__ C) {
  constexpr int K = 4096, nk = 64, ldc = 4096;
  __shared__ __align__(16) us Ab[2][128 * 64];
  __shared__ __align__(16) us Bb[2][128 * 64];
  const int tid = threadIdx.x, lane = tid & 63, w = tid >> 6;
  const int wm = w & 1, wn = w >> 1;
  const int lr = lane & 15, lg = lane >> 4;

  const int xcd = (int)blockIdx.x & 7;
  const int i2 = (int)blockIdx.x >> 3;             // 0..63
  const long m0 = (long)(i2 & 15) * 128;
  const long n0 = (long)(xcd * 4 + (i2 >> 4)) * 128;

  const int rA0 = tid >> 3;                        // rows rA0 + l*32
  const int sc0 = ((tid & 7) ^ (rA0 & 7)) << 3;

  const us* Asrc = A + m0 * K;
  const us* Bsrc = W + n0 * K;

#define STG1(Sb, buf, src)                                               \
  do {                                                                   \
    const us* _s = (src);                                                \
    _Pragma("unroll") for (int l = 0; l < 4; ++l)                        \
      gload16(_s + (long)(rA0 + l * 32) * K + sc0,                       \
              &Sb[buf][(l * 256 + tid) * 8]);                            \
  } while (0)

  const int ra = wm * 64 + lr;
  const int rb = wn * 64 + lr;
  const int offA0 = ra * 64 + ((lg ^ (ra & 7)) << 3);
  const int offA1 = ra * 64 + (((4 + lg) ^ (ra & 7)) << 3);
  const int offB0 = rb * 64 + ((lg ^ (rb & 7)) << 3);
  const int offB1 = rb * 64 + (((4 + lg) ^ (rb & 7)) << 3);

  f4v acc[4][4];
#pragma unroll
  for (int f = 0; f < 4; ++f)
#pragma unroll
    for (int g = 0; g < 4; ++g) acc[f][g] = (f4v){0.f, 0.f, 0.f, 0.f};

  STG1(Ab, 0, Asrc);
  STG1(Bb, 0, Bsrc);
  STG1(Ab, 1, Asrc + 64);
  asm volatile("s_waitcnt vmcnt(4)" ::: "memory");
  BARRIER();

  for (int kt = 0; kt < nk; ++kt) {
    const int d = kt & 1;
    const bool p1 = (kt + 1 < nk), p2 = (kt + 2 < nk);

    s8v a[4][2], b[4][2];
#pragma unroll
    for (int f = 0; f < 4; ++f) {
      a[f][0] = *(const s8v*)(&Ab[d][offA0 + f * 1024]);
      a[f][1] = *(const s8v*)(&Ab[d][offA1 + f * 1024]);
    }
#pragma unroll
    for (int g = 0; g < 4; ++g) {
      b[g][0] = *(const s8v*)(&Bb[d][offB0 + g * 1024]);
      b[g][1] = *(const s8v*)(&Bb[d][offB1 + g * 1024]);
    }
    if (p1) STG1(Bb, d ^ 1, Bsrc + (long)(kt + 1) * 64);
    asm volatile("s_waitcnt lgkmcnt(0)" ::: "memory");
    BARRIER();
    if (p2) STG1(Ab, d, Asrc + (long)(kt + 2) * 64);

    __builtin_amdgcn_s_setprio(1);
#pragma unroll
    for (int f = 0; f < 4; ++f)
#pragma unroll
      for (int g = 0; g < 4; ++g) {
        f4v t = acc[f][g];
        t = __builtin_amdgcn_mfma_f32_16x16x32_bf16(a[f][0], b[g][0], t, 0, 0, 0);
        t = __builtin_amdgcn_mfma_f32_16x16x32_bf16(a[f][1], b[g][1], t, 0, 0, 0);
        acc[f][g] = t;
      }
    __builtin_amdgcn_s_setprio(0);

    if (p2) asm volatile("s_waitcnt vmcnt(4)" ::: "memory");
    else    asm volatile("s_waitcnt vmcnt(0)" ::: "memory");
    BARRIER();
  }

#pragma unroll
  for (int f = 0; f < 4; ++f) {
    long row = m0 + wm * 64 + f * 16 + lg * 4;
#pragma unroll
    for (int g = 0; g < 4; ++g) {
      long col = n0 + wn * 64 + g * 16 + lr;
      f4v v = acc[f][g];
#pragma unroll
      for (int r = 0; r < 4; ++r) C[(row + r) * ldc + col] = v[r];
    }
  }
#undef STG1
}

// ---------------------------------------------------------------------------
// Flash attention (no mask), GQA 4:1. Block = 8 waves = 128 q-rows; 64-key
// tiles. Q AND K RMSNorm+RoPE fused (K transform in the staging path; final
// LDS layout identical to the old gload_lds path: logical chunk j of row r
// stored at physical chunk j^(r&7)). T13 defer-max (THR=8, exp2 domain).
// ---------------------------------------------------------------------------
__global__ __launch_bounds__(512) void attn_k(const us* __restrict__ qkv,
                                              us* __restrict__ ao,
                                              const float* __restrict__ fc,
                                              const float* __restrict__ qw,
                                              const float* __restrict__ kw) {
  __shared__ us Kt[64 * 128];   // [key][d], rows 256B, XOR-swizzled
  __shared__ us Vt[128 * 72];   // [d][key], padded rows (144B)
  __shared__ us Pl[8 * 1024];   // per-wave 16x64 P, XOR-swizzled

  const int bid = blockIdx.x;
  const int qt = bid & 7;
  const int h = (bid >> 3) & 31;
  const int b = bid >> 8;
  const int kvh = h >> 2;
  const int tid = threadIdx.x, lane = tid & 63, w = tid >> 6;
  const int lr = lane & 15, lg = lane >> 4;

  // ---- Q prologue: load raw Q frags, apply RMSNorm + RoPE in-register ----
  const int srow = qt * 128 + w * 16 + lr;
  const us* Qb = qkv + (long)(b * 1024 + srow) * 6144 + h * 128;
  s8v qr[4];
#pragma unroll
  for (int ks = 0; ks < 4; ++ks) qr[ks] = *(const s8v*)(Qb + ks * 32 + lg * 8);

  float ssq = 0.f;
#pragma unroll
  for (int ks = 0; ks < 4; ++ks)
#pragma unroll
    for (int j = 0; j < 8; ++j) {
      float x = b2f((us)qr[ks][j]);
      ssq += x * x;
    }
  ssq += __shfl_xor(ssq, 16);
  ssq += __shfl_xor(ssq, 32);
  const float rr = rsqrtf(ssq * (1.0f / 128.0f) + 1e-6f);

  const float* cosp = fc + (long)srow * 128;
  const float* sinp = fc + 1024 * 128 + (long)srow * 128;
  s8v qf[4];
#pragma unroll
  for (int ks = 0; ks < 4; ++ks) {
    const int d0 = ks * 32 + lg * 8;
    const int dp = d0 ^ 64;
    const float sgn = (ks < 2) ? -1.f : 1.f;
#pragma unroll
    for (int j = 0; j < 8; ++j) {
      float y  = b2f((us)qr[ks][j])     * rr * qw[d0 + j];
      float yp = b2f((us)qr[ks ^ 2][j]) * rr * qw[dp + j];
      float e = y * cosp[d0 + j] + yp * sgn * sinp[d0 + j];
      qf[ks][j] = (short)f2b(e);
    }
  }

  f4v o[8];
#pragma unroll
  for (int n = 0; n < 8; ++n) o[n] = (f4v){0.f, 0.f, 0.f, 0.f};
  float m[4], l[4];
#pragma unroll
  for (int r = 0; r < 4; ++r) { m[r] = -1e30f; l[r] = 0.f; }

  const float SL = 0.08838834764831845f * 1.4426950408889634f;  // D^-1/2 * log2e
  const long krow = (long)b * 1024 * 6144 + 4096 + kvh * 128;
  const long vrow = (long)b * 1024 * 6144 + 5120 + kvh * 128;

  for (int kt = 0; kt < 16; ++kt) {
    __syncthreads();
    // ---- stage K tile with fused RMSNorm + RoPE (raw K -> regs -> LDS) ----
#pragma unroll
    for (int t = 0; t < 2; ++t) {
      int c = t * 512 + tid;
      int row = c >> 4, j = c & 15;              // j == tid & 15 (lane-local)
      s8v kr = *(const s8v*)(qkv + krow + (long)(kt * 64 + row) * 6144 + j * 8);
      float x[8], ssk = 0.f;
#pragma unroll
      for (int i = 0; i < 8; ++i) { x[i] = b2f((us)kr[i]); ssk += x[i] * x[i]; }
#pragma unroll
      for (int off = 1; off < 16; off <<= 1) ssk += __shfl_xor(ssk, off);
      float rk = rsqrtf(ssk * (1.0f / 128.0f) + 1e-6f);
      float y[8];
#pragma unroll
      for (int i = 0; i < 8; ++i) y[i] = x[i] * rk * kw[j * 8 + i];
      int skr = kt * 64 + row;
      const float* ck = fc + (long)skr * 128 + j * 8;
      const float* sk = fc + 1024 * 128 + (long)skr * 128 + j * 8;
      const float sgn = (j < 8) ? -1.f : 1.f;
      s8v ko;
#pragma unroll
      for (int i = 0; i < 8; ++i) {
        float py = __shfl(y[i], lane ^ 8);       // partner chunk j^8, same row
        ko[i] = (short)f2b(y[i] * ck[i] + py * sgn * sk[i]);
      }
      *(s8v*)&Kt[row * 128 + ((j ^ (row & 7)) << 3)] = ko;
    }
    // ---- stage V transposed (512 pair-chunks, 1 per thread) ----
    {
      int c = tid;
      int kp = c & 31;
      int d0 = (c >> 5) * 8;
      const us* vsrc = qkv + vrow + (long)(kt * 64) * 6144 + d0;
      s8v va = *(const s8v*)(vsrc + (long)(2 * kp) * 6144);
      s8v vb = *(const s8v*)(vsrc + (long)(2 * kp + 1) * 6144);
#pragma unroll
      for (int i = 0; i < 8; ++i) {
        unsigned pk = (unsigned)(us)va[i] | ((unsigned)(us)vb[i] << 16);
        *(unsigned*)&Vt[(d0 + i) * 72 + 2 * kp] = pk;
      }
    }
    __syncthreads();

    // ---- S = Q K^T ----
    f4v sacc[4];
#pragma unroll
    for (int j = 0; j < 4; ++j) sacc[j] = (f4v){0.f, 0.f, 0.f, 0.f};
    __builtin_amdgcn_s_setprio(1);
#pragma unroll
    for (int ks = 0; ks < 4; ++ks) {
#pragma unroll
      for (int j = 0; j < 4; ++j) {
        int key = j * 16 + lr;
        s8v kf = *(const s8v*)&Kt[key * 128 + (((ks * 64 + lg * 16) ^ ((key & 7) << 4)) >> 1)];
        sacc[j] = __builtin_amdgcn_mfma_f32_16x16x32_bf16(qf[ks], kf, sacc[j], 0, 0, 0);
      }
    }
    __builtin_amdgcn_s_setprio(0);

    // ---- online softmax (exp2 domain), T13 defer-max ----
    float sm[4];
#pragma unroll
    for (int r = 0; r < 4; ++r)
      sm[r] = fmaxf(fmaxf(sacc[0][r], sacc[1][r]), fmaxf(sacc[2][r], sacc[3][r]));
#pragma unroll
    for (int off = 1; off < 16; off <<= 1)
#pragma unroll
      for (int r = 0; r < 4; ++r) sm[r] = fmaxf(sm[r], __shfl_xor(sm[r], off));
    bool ok = true;
#pragma unroll
    for (int r = 0; r < 4; ++r) ok = ok && (sm[r] * SL <= m[r] + 8.f);
    if (!__all(ok)) {
#pragma unroll
      for (int r = 0; r < 4; ++r) {
        float nm = fmaxf(m[r], sm[r] * SL);
        float alpha = exp2f(m[r] - nm);
        m[r] = nm;
        l[r] *= alpha;
#pragma unroll
        for (int n = 0; n < 8; ++n) o[n][r] *= alpha;
      }
    }

    us* pw = Pl + w * 1024;
#pragma unroll
    for (int j = 0; j < 4; ++j)
#pragma unroll
      for (int r = 0; r < 4; ++r) {
        float p = exp2f(sacc[j][r] * SL - m[r]);
        l[r] += p;
        int prow = lg * 4 + r, pcol = j * 16 + lr;
        pw[(prow * 128 + ((pcol * 2) ^ ((prow & 7) << 4))) >> 1] = f2b(p);
      }

    // ---- O += P V ----
    __builtin_amdgcn_s_setprio(1);
#pragma unroll
    for (int ks = 0; ks < 2; ++ks) {
      int bo = ks * 64 + lg * 16;
      s8v pf = *(const s8v*)&Pl[w * 1024 + ((lr * 128 + (bo ^ ((lr & 7) << 4))) >> 1)];
#pragma unroll
      for (int n = 0; n < 8; ++n) {
        s8v vf = *(const s8v*)&Vt[(n * 16 + lr) * 72 + ks * 32 + lg * 8];
        o[n] = __builtin_amdgcn_mfma_f32_16x16x32_bf16(pf, vf, o[n], 0, 0, 0);
      }
    }
    __builtin_amdgcn_s_setprio(0);
  }

#pragma unroll
  for (int off = 1; off < 16; off <<= 1)
#pragma unroll
    for (int r = 0; r < 4; ++r) l[r] += __shfl_xor(l[r], off);
  float inv[4];
#pragma unroll
  for (int r = 0; r < 4; ++r) inv[r] = 1.f / l[r];
  const long ob = (long)(b * 1024 + qt * 128 + w * 16) * 4096 + h * 128;
#pragma unroll
  for (int n = 0; n < 8; ++n)
#pragma unroll
    for (int r = 0; r < 4; ++r)
      ao[ob + (long)(lg * 4 + r) * 4096 + n * 16 + lr] = f2b(o[n][r] * inv[r]);
}

// ---------------------------------------------------------------------------
// Launch
// ---------------------------------------------------------------------------
extern "C" void kernel_launch(void* const* d_in, const int* in_sizes, int n_in,
                              void* d_out, int out_size, void* d_ws, size_t ws_size,
                              hipStream_t stream) {
  const float* hidden = (const float*)d_in[0];
  const float* fc     = (const float*)d_in[1];
  const float* Wq     = (const float*)d_in[2];
  const float* Wk     = (const float*)d_in[3];
  const float* Wv     = (const float*)d_in[4];
  const float* Wo     = (const float*)d_in[5];
  const float* qw     = (const float*)d_in[6];
  const float* kw     = (const float*)d_in[7];

  us* hb  = (us*)d_ws;                          // [2048][4096] bf16
  us* wb  = hb + (long)2048 * 4096;             // [10240][4096] bf16 (Wq|Wk|Wv|Wo)
  us* wbo = wb + (long)6144 * 4096;             // Wo bf16 [4096][4096]
  us* qkv = wbo + (long)4096 * 4096;            // [2048][6144] bf16
  us* ao  = qkv + (long)2048 * 6144;            // [2048][4096] bf16

  // convert hidden|Wq|Wk|Wv -> contiguous bf16 at hb (Wo converted in-gemm)
  cvt_all_k<<<16384, 256, 0, stream>>>(hidden, Wq, Wk, Wv, hb);

  // fused QKV projection (192 gemm blocks) + Wo convert (64 tail blocks)
  gemm8p<128, false, true><<<256, 512, 0, stream>>>(
      hb, wb, qkv, 4096, 64, 6144, 4, 6, 4, 192, Wo, wbo);

  // flash attention (Q+K rms+rope fused, 128 q-rows/block) -> bf16 [2048][4096]
  attn_k<<<512, 512, 0, stream>>>(qkv, ao, fc, qw, kw);

  // output projection: 128x128 tiles, 512 blocks (2 blocks/CU), 1 pair/K-tile
  gemm2p128<<<512, 256, 0, stream>>>(ao, wbo, (float*)d_out);
}

// Round 14
// 295.606 us; speedup vs baseline: 1.1395x; 1.1395x over previous
//
#include <hip/hip_runtime.h>

// ---------------------------------------------------------------------------
// Qwen3-style attention block on MI355X (gfx950), bf16 MFMA pipeline.
// B=2, S=1024, HID=4096, H=32, KV=8, D=128.
// Stages: cvt(h,Wq,Wk,Wv) -> QKV GEMM (+Wo-cvt tail) -> K-RMSNorm+RoPE
//         -> flash attn (Q-RMSNorm+RoPE fused) -> out GEMM (gemm2p128).
// v14 = round-12 (292.6us best) + ONE delta: m201-exact QKV read schedule
// (phase-4 b0 re-read + phase-1 lgkmcnt(8) throttle). R13's K-fusion into
// attn reverted (32x-redundant transform + bank conflicts; rms_rope_k is
// the right design).
// ---------------------------------------------------------------------------

typedef __attribute__((ext_vector_type(8))) short s8v;            // 8 bf16 (4 VGPR)
typedef __attribute__((ext_vector_type(4))) float f4v;
typedef __attribute__((ext_vector_type(8))) unsigned short u8v;
typedef __attribute__((ext_vector_type(4))) float float4v;
typedef __attribute__((ext_vector_type(2))) float float2v;
typedef unsigned short us;

#define SB() __builtin_amdgcn_sched_barrier(0)

__device__ __forceinline__ void BARRIER() {
  asm volatile("" ::: "memory");
  __builtin_amdgcn_s_barrier();
  asm volatile("" ::: "memory");
}

__device__ __forceinline__ us f2b(float f) {
  unsigned u = __builtin_bit_cast(unsigned, f);
  u += 0x7fffu + ((u >> 16) & 1u);            // round-to-nearest-even
  return (us)(u >> 16);
}
__device__ __forceinline__ float b2f(us h) {
  return __builtin_bit_cast(float, (unsigned)h << 16);
}

__device__ __forceinline__ void gload16(const void* g, void* l) {
  __builtin_amdgcn_global_load_lds(
      (const __attribute__((address_space(1))) unsigned int*)g,
      (__attribute__((address_space(3))) unsigned int*)l, 16, 0, 0);
}

// ---------------------------------------------------------------------------
// Fused f32 -> bf16 convert: hidden|Wq|Wk|Wv, contiguous bf16 destination.
// ---------------------------------------------------------------------------
__global__ __launch_bounds__(256) void cvt_all_k(const float* __restrict__ h,
                                                 const float* __restrict__ wq,
                                                 const float* __restrict__ wk,
                                                 const float* __restrict__ wv,
                                                 us* __restrict__ dst) {
  long blk = blockIdx.x;
  const float* src;
  long off;
  if (blk < 4096)        { src = h;  off = 0; }
  else if (blk < 12288)  { src = wq; off = 4096; }
  else if (blk < 14336)  { src = wk; off = 12288; }
  else                   { src = wv; off = 14336; }
  long i = (blk - off) * 2048 + (long)threadIdx.x * 8;
  long o = blk * 2048 + (long)threadIdx.x * 8;
  float4v a = *(const float4v*)(src + i);
  float4v b = *(const float4v*)(src + i + 4);
  u8v v;
  v[0] = f2b(a[0]); v[1] = f2b(a[1]); v[2] = f2b(a[2]); v[3] = f2b(a[3]);
  v[4] = f2b(b[0]); v[5] = f2b(b[1]); v[6] = f2b(b[2]); v[7] = f2b(b[3]);
  *(u8v*)(dst + o) = v;
}

// ---------------------------------------------------------------------------
// m201-style 8-phase bf16 GEMM (QKV): C[M,N] = A[M,K] * W[N,K]^T
// 256x256 tile, 16x16x32 MFMA, counted vmcnt, chunk-XOR swizzle.
// v14: m201-exact reads (12,4,8,4; lgkmcnt(8) throttle on the 12-read phase).
// ---------------------------------------------------------------------------
template <int AH, bool F32OUT, bool CVTTAIL>
__global__ __launch_bounds__(512, 2) void gemm8p(const us* __restrict__ A,
                                                 const us* __restrict__ W,
                                                 void* __restrict__ Cv,
                                                 int K, int nkt, int ldc,
                                                 int cm, int cn, int ncn,
                                                 int nGemm,
                                                 const float* __restrict__ csrc,
                                                 us* __restrict__ cdst) {
  if constexpr (CVTTAIL) {
    if ((int)blockIdx.x >= nGemm) {
      long c = (long)((int)blockIdx.x - nGemm) * 512 + threadIdx.x;
      for (; c < 2097152; c += 64 * 512) {      // 16,777,216 elems / 8
        long i = c * 8;
        float4v x = *(const float4v*)(csrc + i);
        float4v y = *(const float4v*)(csrc + i + 4);
        u8v v;
        v[0] = f2b(x[0]); v[1] = f2b(x[1]); v[2] = f2b(x[2]); v[3] = f2b(x[3]);
        v[4] = f2b(y[0]); v[5] = f2b(y[1]); v[6] = f2b(y[2]); v[7] = f2b(y[3]);
        *(u8v*)(cdst + i) = v;
      }
      return;
    }
  }

  constexpr int FR = AH / 32;
  constexpr int LA = AH / 64;
  constexpr int VM = 2 * LA + 2;

  __shared__ __align__(16) us Ah[2][2][AH * 64];
  __shared__ __align__(16) us Bh[2][2][128 * 64];
  const int tid = threadIdx.x, lane = tid & 63, w = tid >> 6;
  const int wr = w >> 2, wc = w & 3;
  const int lr = lane & 15, lg = lane >> 4;

  const int xcd = (int)blockIdx.x & 7;
  const int i2 = (int)blockIdx.x >> 3;
  const int im = i2 % cm, itn = i2 / cm;
  const long m0 = (long)((xcd / ncn) * cm + im) * (2 * AH);
  const long n0 = (long)((xcd % ncn) * cn + itn) * 256;

  const int rA0 = tid >> 3;
  const int sc0 = ((tid & 7) ^ (rA0 & 7)) << 3;

#define STGH(dst, src, LOADS)                                           \
  do {                                                                  \
    const us* _s = (src);                                               \
    us* _d = (dst);                                                     \
    _Pragma("unroll") for (int l = 0; l < (LOADS); ++l)                 \
      gload16(_s + (long)(rA0 + l * 64) * K + sc0, _d + (l * 512 + tid) * 8); \
  } while (0)

  const us* Asrc = A + m0 * K;
  const us* Bsrc = W + n0 * K;
  const long hKA = (long)AH * K;
  const long hKB = (long)128 * K;

  const int ra = wr * (AH / 2) + lr, rb = wc * 32 + lr;
  const int offA0 = ra * 64 + ((lg ^ (ra & 7)) << 3);
  const int offA1 = ra * 64 + (((4 + lg) ^ (ra & 7)) << 3);
  const int offB0 = rb * 64 + ((lg ^ (rb & 7)) << 3);
  const int offB1 = rb * 64 + (((4 + lg) ^ (rb & 7)) << 3);

  f4v acc[2 * FR][4];
#pragma unroll
  for (int i = 0; i < 2 * FR; ++i)
#pragma unroll
    for (int j = 0; j < 4; ++j) acc[i][j] = (f4v){0.f, 0.f, 0.f, 0.f};

  const int nk = nkt;

  STGH(Ah[0][0], Asrc, LA);
  STGH(Bh[0][0], Bsrc, 2);
  STGH(Bh[0][1], Bsrc + hKB, 2);
  STGH(Ah[0][1], Asrc + hKA, LA);
  STGH(Ah[1][0], Asrc + 64, LA);
  STGH(Bh[1][1], Bsrc + hKB + 64, 2);
  STGH(Ah[1][1], Asrc + hKA + 64, LA);
  asm volatile("s_waitcnt vmcnt(%0)" :: "i"(VM) : "memory");
  BARRIER();

  s8v a[FR][2], b0[2][2], b1[2][2];

#define RD_A(H)                                                         \
  _Pragma("unroll") for (int f = 0; f < FR; ++f) {                      \
    a[f][0] = *(const s8v*)(&Ah[d][H][offA0 + f * 1024]);               \
    a[f][1] = *(const s8v*)(&Ah[d][H][offA1 + f * 1024]);               \
  }
#define RD_B(BB, H)                                                     \
  _Pragma("unroll") for (int g = 0; g < 2; ++g) {                       \
    BB[g][0] = *(const s8v*)(&Bh[d][H][offB0 + g * 1024]);              \
    BB[g][1] = *(const s8v*)(&Bh[d][H][offB1 + g * 1024]);              \
  }
#define QUAD(QM, QN, BB)                                                \
  __builtin_amdgcn_s_setprio(1);                                        \
  _Pragma("unroll") for (int f = 0; f < FR; ++f)                        \
  _Pragma("unroll") for (int g = 0; g < 2; ++g) {                       \
    f4v t = acc[QM * FR + f][QN * 2 + g];                               \
    t = __builtin_amdgcn_mfma_f32_16x16x32_bf16(a[f][0], BB[g][0], t, 0, 0, 0); \
    t = __builtin_amdgcn_mfma_f32_16x16x32_bf16(a[f][1], BB[g][1], t, 0, 0, 0); \
    acc[QM * FR + f][QN * 2 + g] = t;                                   \
  }                                                                     \
  __builtin_amdgcn_s_setprio(0);
#define PREMFMA()                                                       \
  BARRIER();                                                            \
  asm volatile("s_waitcnt lgkmcnt(0)" ::: "memory");                    \
  SB();

  for (int kt = 0; kt < nk; ++kt) {
    const int d = kt & 1;
    const long kb2 = (long)(kt + 2) * 64;
    const bool p1 = (kt + 1 < nk), p2 = (kt + 2 < nk);

    // ---- phase 1: q(0,0); 12 reads; stage B0(kt+1); lgkm throttle ----
    RD_A(0)
    RD_B(b0, 0)
    if (p1) STGH(Bh[d ^ 1][0], Bsrc + (long)(kt + 1) * 64, 2);
    asm volatile("s_waitcnt lgkmcnt(8)" ::: "memory");
    PREMFMA()
    QUAD(0, 0, b0)
    BARRIER();

    // ---- phase 2: q(0,1); 4 reads; stage A0(kt+2) ----
    RD_B(b1, 1)
    if (p2) STGH(Ah[d][0], Asrc + kb2, LA);
    PREMFMA()
    QUAD(0, 1, b1)
    BARRIER();

    // ---- phase 3: q(1,1); 8 reads; stage B1(kt+2) ----
    RD_A(1)
    if (p2) STGH(Bh[d][1], Bsrc + hKB + kb2, 2);
    PREMFMA()
    QUAD(1, 1, b1)
    BARRIER();

    // ---- phase 4: q(1,0); 4 reads (B0 re-read, m201-exact); stage A1 ----
    RD_B(b0, 0)
    if (p2) STGH(Ah[d][1], Asrc + hKA + kb2, LA);
    PREMFMA()
    QUAD(1, 0, b0)
    if (p2) asm volatile("s_waitcnt vmcnt(%0)" :: "i"(VM) : "memory");
    else    asm volatile("s_waitcnt vmcnt(0)" ::: "memory");
    BARRIER();
  }

#pragma unroll
  for (int qm = 0; qm < 2; ++qm)
#pragma unroll
    for (int f = 0; f < FR; ++f) {
      long row = m0 + qm * AH + wr * (AH / 2) + f * 16 + lg * 4;
#pragma unroll
      for (int qn = 0; qn < 2; ++qn)
#pragma unroll
        for (int g = 0; g < 2; ++g) {
          long col = n0 + qn * 128 + wc * 32 + g * 16 + lr;
          f4v v = acc[qm * FR + f][qn * 2 + g];
          if constexpr (F32OUT) {
            float* C = (float*)Cv;
#pragma unroll
            for (int r = 0; r < 4; ++r) C[(row + r) * ldc + col] = v[r];
          } else {
            us* C = (us*)Cv;
#pragma unroll
            for (int r = 0; r < 4; ++r) C[(row + r) * ldc + col] = f2b(v[r]);
          }
        }
    }
#undef STGH
#undef RD_A
#undef RD_B
#undef QUAD
#undef PREMFMA
}

// ---------------------------------------------------------------------------
// gemm2p128 (out-proj): C[2048,4096] f32 = A[2048,K]bf16 * W[4096,K]^T
// (round-10/12 core: 128x128 tile, 4 waves, 16x16x32 MFMA, 2 blocks/CU)
// ---------------------------------------------------------------------------
__global__ __launch_bounds__(256, 2) void gemm2p128(const us* __restrict__ A,
                                                    const us* __restrict__ W,
                                                    float* __restrict__ C) {
  constexpr int K = 4096, nk = 64, ldc = 4096;
  __shared__ __align__(16) us Ab[2][128 * 64];
  __shared__ __align__(16) us Bb[2][128 * 64];
  const int tid = threadIdx.x, lane = tid & 63, w = tid >> 6;
  const int wm = w & 1, wn = w >> 1;
  const int lr = lane & 15, lg = lane >> 4;

  const int xcd = (int)blockIdx.x & 7;
  const int i2 = (int)blockIdx.x >> 3;             // 0..63
  const long m0 = (long)(i2 & 15) * 128;
  const long n0 = (long)(xcd * 4 + (i2 >> 4)) * 128;

  const int rA0 = tid >> 3;                        // rows rA0 + l*32
  const int sc0 = ((tid & 7) ^ (rA0 & 7)) << 3;

  const us* Asrc = A + m0 * K;
  const us* Bsrc = W + n0 * K;

#define STG1(Sb, buf, src)                                               \
  do {                                                                   \
    const us* _s = (src);                                                \
    _Pragma("unroll") for (int l = 0; l < 4; ++l)                        \
      gload16(_s + (long)(rA0 + l * 32) * K + sc0,                       \
              &Sb[buf][(l * 256 + tid) * 8]);                            \
  } while (0)

  const int ra = wm * 64 + lr;
  const int rb = wn * 64 + lr;
  const int offA0 = ra * 64 + ((lg ^ (ra & 7)) << 3);
  const int offA1 = ra * 64 + (((4 + lg) ^ (ra & 7)) << 3);
  const int offB0 = rb * 64 + ((lg ^ (rb & 7)) << 3);
  const int offB1 = rb * 64 + (((4 + lg) ^ (rb & 7)) << 3);

  f4v acc[4][4];
#pragma unroll
  for (int f = 0; f < 4; ++f)
#pragma unroll
    for (int g = 0; g < 4; ++g) acc[f][g] = (f4v){0.f, 0.f, 0.f, 0.f};

  STG1(Ab, 0, Asrc);
  STG1(Bb, 0, Bsrc);
  STG1(Ab, 1, Asrc + 64);
  asm volatile("s_waitcnt vmcnt(4)" ::: "memory");
  BARRIER();

  for (int kt = 0; kt < nk; ++kt) {
    const int d = kt & 1;
    const bool p1 = (kt + 1 < nk), p2 = (kt + 2 < nk);

    s8v a[4][2], b[4][2];
#pragma unroll
    for (int f = 0; f < 4; ++f) {
      a[f][0] = *(const s8v*)(&Ab[d][offA0 + f * 1024]);
      a[f][1] = *(const s8v*)(&Ab[d][offA1 + f * 1024]);
    }
#pragma unroll
    for (int g = 0; g < 4; ++g) {
      b[g][0] = *(const s8v*)(&Bb[d][offB0 + g * 1024]);
      b[g][1] = *(const s8v*)(&Bb[d][offB1 + g * 1024]);
    }
    if (p1) STG1(Bb, d ^ 1, Bsrc + (long)(kt + 1) * 64);
    asm volatile("s_waitcnt lgkmcnt(0)" ::: "memory");
    BARRIER();
    if (p2) STG1(Ab, d, Asrc + (long)(kt + 2) * 64);

    __builtin_amdgcn_s_setprio(1);
#pragma unroll
    for (int f = 0; f < 4; ++f)
#pragma unroll
      for (int g = 0; g < 4; ++g) {
        f4v t = acc[f][g];
        t = __builtin_amdgcn_mfma_f32_16x16x32_bf16(a[f][0], b[g][0], t, 0, 0, 0);
        t = __builtin_amdgcn_mfma_f32_16x16x32_bf16(a[f][1], b[g][1], t, 0, 0, 0);
        acc[f][g] = t;
      }
    __builtin_amdgcn_s_setprio(0);

    if (p2) asm volatile("s_waitcnt vmcnt(4)" ::: "memory");
    else    asm volatile("s_waitcnt vmcnt(0)" ::: "memory");
    BARRIER();
  }

#pragma unroll
  for (int f = 0; f < 4; ++f) {
    long row = m0 + wm * 64 + f * 16 + lg * 4;
#pragma unroll
    for (int g = 0; g < 4; ++g) {
      long col = n0 + wn * 64 + g * 16 + lr;
      f4v v = acc[f][g];
#pragma unroll
      for (int r = 0; r < 4; ++r) C[(row + r) * ldc + col] = v[r];
    }
  }
#undef STG1
}

// ---------------------------------------------------------------------------
// Per-head RMSNorm (D=128) + RoPE for K HEADS ONLY, in-place, vectorized.
// ---------------------------------------------------------------------------
__global__ __launch_bounds__(256) void rms_rope_k(us* __restrict__ qkv,
                                                  const float* __restrict__ fc,
                                                  const float* __restrict__ kw) {
  int idx = blockIdx.x * 4 + (threadIdx.x >> 6);
  int lane = threadIdx.x & 63;
  int head = idx & 7;                  // 8 K heads
  int row = idx >> 3;                  // b*1024 + s
  int s = row & 1023;
  us* p = qkv + (long)row * 6144 + 4096 + head * 128;

  unsigned v = ((const unsigned*)p)[lane];
  float x0 = b2f((us)(v & 0xffff)), x1 = b2f((us)(v >> 16));
  float ss = x0 * x0 + x1 * x1;
#pragma unroll
  for (int off = 32; off; off >>= 1) ss += __shfl_xor(ss, off);
  float r = rsqrtf(ss * (1.0f / 128.0f) + 1e-6f);
  float2v wv = ((const float2v*)kw)[lane];
  float y0 = x0 * r * wv[0], y1 = x1 * r * wv[1];
  float py0 = __shfl(y0, lane ^ 32);
  float py1 = __shfl(y1, lane ^ 32);
  float2v cv = ((const float2v*)(fc + (long)s * 128))[lane];
  const float* sbase = (lane < 32) ? (fc + 2 * 1024 * 128) : (fc + 1024 * 128);
  float2v sv = ((const float2v*)(sbase + (long)s * 128))[lane];
  float e0 = y0 * cv[0] + py0 * sv[0];
  float e1 = y1 * cv[1] + py1 * sv[1];
  ((unsigned*)p)[lane] = (unsigned)f2b(e0) | ((unsigned)f2b(e1) << 16);
}

// ---------------------------------------------------------------------------
// Flash attention (no mask), GQA 4:1. Block = 8 waves = 128 q-rows; 64-key
// tiles. Q RMSNorm+RoPE fused in the prologue. T13 defer-max (THR=8).
// (round-12 core, verbatim)
// ---------------------------------------------------------------------------
__global__ __launch_bounds__(512) void attn_k(const us* __restrict__ qkv,
                                              us* __restrict__ ao,
                                              const float* __restrict__ fc,
                                              const float* __restrict__ qw) {
  __shared__ us Kt[64 * 128];   // [key][d], rows 256B, XOR-swizzled
  __shared__ us Vt[128 * 72];   // [d][key], padded rows (144B)
  __shared__ us Pl[8 * 1024];   // per-wave 16x64 P, XOR-swizzled

  const int bid = blockIdx.x;
  const int qt = bid & 7;
  const int h = (bid >> 3) & 31;
  const int b = bid >> 8;
  const int kvh = h >> 2;
  const int tid = threadIdx.x, lane = tid & 63, w = tid >> 6;
  const int lr = lane & 15, lg = lane >> 4;

  const int srow = qt * 128 + w * 16 + lr;
  const us* Qb = qkv + (long)(b * 1024 + srow) * 6144 + h * 128;
  s8v qr[4];
#pragma unroll
  for (int ks = 0; ks < 4; ++ks) qr[ks] = *(const s8v*)(Qb + ks * 32 + lg * 8);

  float ssq = 0.f;
#pragma unroll
  for (int ks = 0; ks < 4; ++ks)
#pragma unroll
    for (int j = 0; j < 8; ++j) {
      float x = b2f((us)qr[ks][j]);
      ssq += x * x;
    }
  ssq += __shfl_xor(ssq, 16);
  ssq += __shfl_xor(ssq, 32);
  const float rr = rsqrtf(ssq * (1.0f / 128.0f) + 1e-6f);

  const float* cosp = fc + (long)srow * 128;
  const float* sinp = fc + 1024 * 128 + (long)srow * 128;
  s8v qf[4];
#pragma unroll
  for (int ks = 0; ks < 4; ++ks) {
    const int d0 = ks * 32 + lg * 8;
    const int dp = d0 ^ 64;
    const float sgn = (ks < 2) ? -1.f : 1.f;
#pragma unroll
    for (int j = 0; j < 8; ++j) {
      float y  = b2f((us)qr[ks][j])     * rr * qw[d0 + j];
      float yp = b2f((us)qr[ks ^ 2][j]) * rr * qw[dp + j];
      float e = y * cosp[d0 + j] + yp * sgn * sinp[d0 + j];
      qf[ks][j] = (short)f2b(e);
    }
  }

  f4v o[8];
#pragma unroll
  for (int n = 0; n < 8; ++n) o[n] = (f4v){0.f, 0.f, 0.f, 0.f};
  float m[4], l[4];
#pragma unroll
  for (int r = 0; r < 4; ++r) { m[r] = -1e30f; l[r] = 0.f; }

  const float SL = 0.08838834764831845f * 1.4426950408889634f;  // D^-1/2 * log2e
  const long krow = (long)b * 1024 * 6144 + 4096 + kvh * 128;
  const long vrow = (long)b * 1024 * 6144 + 5120 + kvh * 128;

  for (int kt = 0; kt < 16; ++kt) {
    __syncthreads();
#pragma unroll
    for (int t = 0; t < 2; ++t) {
      int c = t * 512 + tid;
      int row = c >> 4;
      int sc = (c & 15) ^ (row & 7);
      gload16(qkv + krow + (long)(kt * 64 + row) * 6144 + sc * 8, &Kt[c * 8]);
    }
    {
      int c = tid;
      int kp = c & 31;
      int d0 = (c >> 5) * 8;
      const us* vsrc = qkv + vrow + (long)(kt * 64) * 6144 + d0;
      s8v va = *(const s8v*)(vsrc + (long)(2 * kp) * 6144);
      s8v vb = *(const s8v*)(vsrc + (long)(2 * kp + 1) * 6144);
#pragma unroll
      for (int i = 0; i < 8; ++i) {
        unsigned pk = (unsigned)(us)va[i] | ((unsigned)(us)vb[i] << 16);
        *(unsigned*)&Vt[(d0 + i) * 72 + 2 * kp] = pk;
      }
    }
    __syncthreads();

    f4v sacc[4];
#pragma unroll
    for (int j = 0; j < 4; ++j) sacc[j] = (f4v){0.f, 0.f, 0.f, 0.f};
    __builtin_amdgcn_s_setprio(1);
#pragma unroll
    for (int ks = 0; ks < 4; ++ks) {
#pragma unroll
      for (int j = 0; j < 4; ++j) {
        int key = j * 16 + lr;
        s8v kf = *(const s8v*)&Kt[key * 128 + (((ks * 64 + lg * 16) ^ ((key & 7) << 4)) >> 1)];
        sacc[j] = __builtin_amdgcn_mfma_f32_16x16x32_bf16(qf[ks], kf, sacc[j], 0, 0, 0);
      }
    }
    __builtin_amdgcn_s_setprio(0);

    float sm[4];
#pragma unroll
    for (int r = 0; r < 4; ++r)
      sm[r] = fmaxf(fmaxf(sacc[0][r], sacc[1][r]), fmaxf(sacc[2][r], sacc[3][r]));
#pragma unroll
    for (int off = 1; off < 16; off <<= 1)
#pragma unroll
      for (int r = 0; r < 4; ++r) sm[r] = fmaxf(sm[r], __shfl_xor(sm[r], off));
    bool ok = true;
#pragma unroll
    for (int r = 0; r < 4; ++r) ok = ok && (sm[r] * SL <= m[r] + 8.f);
    if (!__all(ok)) {
#pragma unroll
      for (int r = 0; r < 4; ++r) {
        float nm = fmaxf(m[r], sm[r] * SL);
        float alpha = exp2f(m[r] - nm);
        m[r] = nm;
        l[r] *= alpha;
#pragma unroll
        for (int n = 0; n < 8; ++n) o[n][r] *= alpha;
      }
    }

    us* pw = Pl + w * 1024;
#pragma unroll
    for (int j = 0; j < 4; ++j)
#pragma unroll
      for (int r = 0; r < 4; ++r) {
        float p = exp2f(sacc[j][r] * SL - m[r]);
        l[r] += p;
        int prow = lg * 4 + r, pcol = j * 16 + lr;
        pw[(prow * 128 + ((pcol * 2) ^ ((prow & 7) << 4))) >> 1] = f2b(p);
      }

    __builtin_amdgcn_s_setprio(1);
#pragma unroll
    for (int ks = 0; ks < 2; ++ks) {
      int bo = ks * 64 + lg * 16;
      s8v pf = *(const s8v*)&Pl[w * 1024 + ((lr * 128 + (bo ^ ((lr & 7) << 4))) >> 1)];
#pragma unroll
      for (int n = 0; n < 8; ++n) {
        s8v vf = *(const s8v*)&Vt[(n * 16 + lr) * 72 + ks * 32 + lg * 8];
        o[n] = __builtin_amdgcn_mfma_f32_16x16x32_bf16(pf, vf, o[n], 0, 0, 0);
      }
    }
    __builtin_amdgcn_s_setprio(0);
  }

#pragma unroll
  for (int off = 1; off < 16; off <<= 1)
#pragma unroll
    for (int r = 0; r < 4; ++r) l[r] += __shfl_xor(l[r], off);
  float inv[4];
#pragma unroll
  for (int r = 0; r < 4; ++r) inv[r] = 1.f / l[r];
  const long ob = (long)(b * 1024 + qt * 128 + w * 16) * 4096 + h * 128;
#pragma unroll
  for (int n = 0; n < 8; ++n)
#pragma unroll
    for (int r = 0; r < 4; ++r)
      ao[ob + (long)(lg * 4 + r) * 4096 + n * 16 + lr] = f2b(o[n][r] * inv[r]);
}

// ---------------------------------------------------------------------------
// Launch
// ---------------------------------------------------------------------------
extern "C" void kernel_launch(void* const* d_in, const int* in_sizes, int n_in,
                              void* d_out, int out_size, void* d_ws, size_t ws_size,
                              hipStream_t stream) {
  const float* hidden = (const float*)d_in[0];
  const float* fc     = (const float*)d_in[1];
  const float* Wq     = (const float*)d_in[2];
  const float* Wk     = (const float*)d_in[3];
  const float* Wv     = (const float*)d_in[4];
  const float* Wo     = (const float*)d_in[5];
  const float* qw     = (const float*)d_in[6];
  const float* kw     = (const float*)d_in[7];

  us* hb  = (us*)d_ws;                          // [2048][4096] bf16
  us* wb  = hb + (long)2048 * 4096;             // [10240][4096] bf16 (Wq|Wk|Wv|Wo)
  us* wbo = wb + (long)6144 * 4096;             // Wo bf16 [4096][4096]
  us* qkv = wbo + (long)4096 * 4096;            // [2048][6144] bf16
  us* ao  = qkv + (long)2048 * 6144;            // [2048][4096] bf16

  // convert hidden|Wq|Wk|Wv -> contiguous bf16 at hb (Wo converted in-gemm)
  cvt_all_k<<<16384, 256, 0, stream>>>(hidden, Wq, Wk, Wv, hb);

  // fused QKV projection (192 gemm blocks) + Wo convert (64 tail blocks)
  gemm8p<128, false, true><<<256, 512, 0, stream>>>(
      hb, wb, qkv, 4096, 64, 6144, 4, 6, 4, 192, Wo, wbo);

  // K-head RMSNorm + RoPE in place (Q handled inside attn)
  rms_rope_k<<<4096, 256, 0, stream>>>(qkv, fc, kw);

  // flash attention (Q rms+rope fused, 128 q-rows/block) -> bf16 [2048][4096]
  attn_k<<<512, 512, 0, stream>>>(qkv, ao, fc, qw);

  // output projection: 128x128 tiles, 512 blocks (2 blocks/CU), 1 pair/K-tile
  gemm2p128<<<512, 256, 0, stream>>>(ao, wbo, (float*)d_out);
}

// Round 15
// 291.934 us; speedup vs baseline: 1.1538x; 1.0126x over previous
//
#include <hip/hip_runtime.h>

// ---------------------------------------------------------------------------
// Qwen3-style attention block on MI355X (gfx950), bf16 MFMA pipeline.
// B=2, S=1024, HID=4096, H=32, KV=8, D=128.
// Stages: cvt(h,Wq,Wk,Wv) -> QKV GEMM (+Wo-cvt tail) -> K-RMSNorm+RoPE
//         -> flash attn (Q-RMSNorm+RoPE fused) -> out GEMM (gemm2p128).
// v15 = round-12 verbatim (best measured: 292.6us). R13's K-fusion and
// R14's m201-exact read schedule both measured as regressions; reverted.
// ---------------------------------------------------------------------------

typedef __attribute__((ext_vector_type(8))) short s8v;            // 8 bf16 (4 VGPR)
typedef __attribute__((ext_vector_type(4))) float f4v;
typedef __attribute__((ext_vector_type(8))) unsigned short u8v;
typedef __attribute__((ext_vector_type(4))) float float4v;
typedef __attribute__((ext_vector_type(2))) float float2v;
typedef unsigned short us;

#define SB() __builtin_amdgcn_sched_barrier(0)

__device__ __forceinline__ void BARRIER() {
  asm volatile("" ::: "memory");
  __builtin_amdgcn_s_barrier();
  asm volatile("" ::: "memory");
}

__device__ __forceinline__ us f2b(float f) {
  unsigned u = __builtin_bit_cast(unsigned, f);
  u += 0x7fffu + ((u >> 16) & 1u);            // round-to-nearest-even
  return (us)(u >> 16);
}
__device__ __forceinline__ float b2f(us h) {
  return __builtin_bit_cast(float, (unsigned)h << 16);
}

__device__ __forceinline__ void gload16(const void* g, void* l) {
  __builtin_amdgcn_global_load_lds(
      (const __attribute__((address_space(1))) unsigned int*)g,
      (__attribute__((address_space(3))) unsigned int*)l, 16, 0, 0);
}

// ---------------------------------------------------------------------------
// Fused f32 -> bf16 convert: hidden|Wq|Wk|Wv, contiguous bf16 destination.
// ---------------------------------------------------------------------------
__global__ __launch_bounds__(256) void cvt_all_k(const float* __restrict__ h,
                                                 const float* __restrict__ wq,
                                                 const float* __restrict__ wk,
                                                 const float* __restrict__ wv,
                                                 us* __restrict__ dst) {
  long blk = blockIdx.x;
  const float* src;
  long off;
  if (blk < 4096)        { src = h;  off = 0; }
  else if (blk < 12288)  { src = wq; off = 4096; }
  else if (blk < 14336)  { src = wk; off = 12288; }
  else                   { src = wv; off = 14336; }
  long i = (blk - off) * 2048 + (long)threadIdx.x * 8;
  long o = blk * 2048 + (long)threadIdx.x * 8;
  float4v a = *(const float4v*)(src + i);
  float4v b = *(const float4v*)(src + i + 4);
  u8v v;
  v[0] = f2b(a[0]); v[1] = f2b(a[1]); v[2] = f2b(a[2]); v[3] = f2b(a[3]);
  v[4] = f2b(b[0]); v[5] = f2b(b[1]); v[6] = f2b(b[2]); v[7] = f2b(b[3]);
  *(u8v*)(dst + o) = v;
}

// ---------------------------------------------------------------------------
// m201-style 8-phase bf16 GEMM (QKV): C[M,N] = A[M,K] * W[N,K]^T
// 256x256 tile, 16x16x32 MFMA, counted vmcnt, chunk-XOR swizzle.
// Round-12 read schedule: 12,4,8,0 (b0 frags resident; phase 4 no reads).
// ---------------------------------------------------------------------------
template <int AH, bool F32OUT, bool CVTTAIL>
__global__ __launch_bounds__(512, 2) void gemm8p(const us* __restrict__ A,
                                                 const us* __restrict__ W,
                                                 void* __restrict__ Cv,
                                                 int K, int nkt, int ldc,
                                                 int cm, int cn, int ncn,
                                                 int nGemm,
                                                 const float* __restrict__ csrc,
                                                 us* __restrict__ cdst) {
  if constexpr (CVTTAIL) {
    if ((int)blockIdx.x >= nGemm) {
      long c = (long)((int)blockIdx.x - nGemm) * 512 + threadIdx.x;
      for (; c < 2097152; c += 64 * 512) {      // 16,777,216 elems / 8
        long i = c * 8;
        float4v x = *(const float4v*)(csrc + i);
        float4v y = *(const float4v*)(csrc + i + 4);
        u8v v;
        v[0] = f2b(x[0]); v[1] = f2b(x[1]); v[2] = f2b(x[2]); v[3] = f2b(x[3]);
        v[4] = f2b(y[0]); v[5] = f2b(y[1]); v[6] = f2b(y[2]); v[7] = f2b(y[3]);
        *(u8v*)(cdst + i) = v;
      }
      return;
    }
  }

  constexpr int FR = AH / 32;
  constexpr int LA = AH / 64;
  constexpr int VM = 2 * LA + 2;

  __shared__ __align__(16) us Ah[2][2][AH * 64];
  __shared__ __align__(16) us Bh[2][2][128 * 64];
  const int tid = threadIdx.x, lane = tid & 63, w = tid >> 6;
  const int wr = w >> 2, wc = w & 3;
  const int lr = lane & 15, lg = lane >> 4;

  const int xcd = (int)blockIdx.x & 7;
  const int i2 = (int)blockIdx.x >> 3;
  const int im = i2 % cm, itn = i2 / cm;
  const long m0 = (long)((xcd / ncn) * cm + im) * (2 * AH);
  const long n0 = (long)((xcd % ncn) * cn + itn) * 256;

  const int rA0 = tid >> 3;
  const int sc0 = ((tid & 7) ^ (rA0 & 7)) << 3;

#define STGH(dst, src, LOADS)                                           \
  do {                                                                  \
    const us* _s = (src);                                               \
    us* _d = (dst);                                                     \
    _Pragma("unroll") for (int l = 0; l < (LOADS); ++l)                 \
      gload16(_s + (long)(rA0 + l * 64) * K + sc0, _d + (l * 512 + tid) * 8); \
  } while (0)

  const us* Asrc = A + m0 * K;
  const us* Bsrc = W + n0 * K;
  const long hKA = (long)AH * K;
  const long hKB = (long)128 * K;

  const int ra = wr * (AH / 2) + lr, rb = wc * 32 + lr;
  const int offA0 = ra * 64 + ((lg ^ (ra & 7)) << 3);
  const int offA1 = ra * 64 + (((4 + lg) ^ (ra & 7)) << 3);
  const int offB0 = rb * 64 + ((lg ^ (rb & 7)) << 3);
  const int offB1 = rb * 64 + (((4 + lg) ^ (rb & 7)) << 3);

  f4v acc[2 * FR][4];
#pragma unroll
  for (int i = 0; i < 2 * FR; ++i)
#pragma unroll
    for (int j = 0; j < 4; ++j) acc[i][j] = (f4v){0.f, 0.f, 0.f, 0.f};

  const int nk = nkt;

  STGH(Ah[0][0], Asrc, LA);
  STGH(Bh[0][0], Bsrc, 2);
  STGH(Bh[0][1], Bsrc + hKB, 2);
  STGH(Ah[0][1], Asrc + hKA, LA);
  STGH(Ah[1][0], Asrc + 64, LA);
  STGH(Bh[1][1], Bsrc + hKB + 64, 2);
  STGH(Ah[1][1], Asrc + hKA + 64, LA);
  asm volatile("s_waitcnt vmcnt(%0)" :: "i"(VM) : "memory");
  BARRIER();

  s8v a[FR][2], b0[2][2], b1[2][2];

#define RD_A(H)                                                         \
  _Pragma("unroll") for (int f = 0; f < FR; ++f) {                      \
    a[f][0] = *(const s8v*)(&Ah[d][H][offA0 + f * 1024]);               \
    a[f][1] = *(const s8v*)(&Ah[d][H][offA1 + f * 1024]);               \
  }
#define RD_B(BB, H)                                                     \
  _Pragma("unroll") for (int g = 0; g < 2; ++g) {                       \
    BB[g][0] = *(const s8v*)(&Bh[d][H][offB0 + g * 1024]);              \
    BB[g][1] = *(const s8v*)(&Bh[d][H][offB1 + g * 1024]);              \
  }
#define QUAD(QM, QN, BB)                                                \
  __builtin_amdgcn_s_setprio(1);                                        \
  _Pragma("unroll") for (int f = 0; f < FR; ++f)                        \
  _Pragma("unroll") for (int g = 0; g < 2; ++g) {                       \
    f4v t = acc[QM * FR + f][QN * 2 + g];                               \
    t = __builtin_amdgcn_mfma_f32_16x16x32_bf16(a[f][0], BB[g][0], t, 0, 0, 0); \
    t = __builtin_amdgcn_mfma_f32_16x16x32_bf16(a[f][1], BB[g][1], t, 0, 0, 0); \
    acc[QM * FR + f][QN * 2 + g] = t;                                   \
  }                                                                     \
  __builtin_amdgcn_s_setprio(0);
#define PREMFMA()                                                       \
  BARRIER();                                                            \
  asm volatile("s_waitcnt lgkmcnt(0)" ::: "memory");                    \
  SB();

  for (int kt = 0; kt < nk; ++kt) {
    const int d = kt & 1;
    const long kb2 = (long)(kt + 2) * 64;
    const bool p1 = (kt + 1 < nk), p2 = (kt + 2 < nk);

    RD_A(0)
    RD_B(b0, 0)
    if (p1) STGH(Bh[d ^ 1][0], Bsrc + (long)(kt + 1) * 64, 2);
    PREMFMA()
    QUAD(0, 0, b0)
    BARRIER();

    RD_B(b1, 1)
    if (p2) STGH(Ah[d][0], Asrc + kb2, LA);
    PREMFMA()
    QUAD(0, 1, b1)
    BARRIER();

    RD_A(1)
    if (p2) STGH(Bh[d][1], Bsrc + hKB + kb2, 2);
    PREMFMA()
    QUAD(1, 1, b1)
    BARRIER();

    if (p2) STGH(Ah[d][1], Asrc + hKA + kb2, LA);
    PREMFMA()
    QUAD(1, 0, b0)
    if (p2) asm volatile("s_waitcnt vmcnt(%0)" :: "i"(VM) : "memory");
    else    asm volatile("s_waitcnt vmcnt(0)" ::: "memory");
    BARRIER();
  }

#pragma unroll
  for (int qm = 0; qm < 2; ++qm)
#pragma unroll
    for (int f = 0; f < FR; ++f) {
      long row = m0 + qm * AH + wr * (AH / 2) + f * 16 + lg * 4;
#pragma unroll
      for (int qn = 0; qn < 2; ++qn)
#pragma unroll
        for (int g = 0; g < 2; ++g) {
          long col = n0 + qn * 128 + wc * 32 + g * 16 + lr;
          f4v v = acc[qm * FR + f][qn * 2 + g];
          if constexpr (F32OUT) {
            float* C = (float*)Cv;
#pragma unroll
            for (int r = 0; r < 4; ++r) C[(row + r) * ldc + col] = v[r];
          } else {
            us* C = (us*)Cv;
#pragma unroll
            for (int r = 0; r < 4; ++r) C[(row + r) * ldc + col] = f2b(v[r]);
          }
        }
    }
#undef STGH
#undef RD_A
#undef RD_B
#undef QUAD
#undef PREMFMA
}

// ---------------------------------------------------------------------------
// gemm2p128 (out-proj): C[2048,4096] f32 = A[2048,K]bf16 * W[4096,K]^T
// 128x128 tile, BK=64, 4 waves, 16x16x32 MFMA, 64 KiB LDS -> 2 blocks/CU.
// One barrier pair per K-tile; counted vmcnt(4); lgkm(0)-pre-barrier WAR.
// ---------------------------------------------------------------------------
__global__ __launch_bounds__(256, 2) void gemm2p128(const us* __restrict__ A,
                                                    const us* __restrict__ W,
                                                    float* __restrict__ C) {
  constexpr int K = 4096, nk = 64, ldc = 4096;
  __shared__ __align__(16) us Ab[2][128 * 64];
  __shared__ __align__(16) us Bb[2][128 * 64];
  const int tid = threadIdx.x, lane = tid & 63, w = tid >> 6;
  const int wm = w & 1, wn = w >> 1;
  const int lr = lane & 15, lg = lane >> 4;

  const int xcd = (int)blockIdx.x & 7;
  const int i2 = (int)blockIdx.x >> 3;             // 0..63
  const long m0 = (long)(i2 & 15) * 128;
  const long n0 = (long)(xcd * 4 + (i2 >> 4)) * 128;

  const int rA0 = tid >> 3;                        // rows rA0 + l*32
  const int sc0 = ((tid & 7) ^ (rA0 & 7)) << 3;

  const us* Asrc = A + m0 * K;
  const us* Bsrc = W + n0 * K;

#define STG1(Sb, buf, src)                                               \
  do {                                                                   \
    const us* _s = (src);                                                \
    _Pragma("unroll") for (int l = 0; l < 4; ++l)                        \
      gload16(_s + (long)(rA0 + l * 32) * K + sc0,                       \
              &Sb[buf][(l * 256 + tid) * 8]);                            \
  } while (0)

  const int ra = wm * 64 + lr;
  const int rb = wn * 64 + lr;
  const int offA0 = ra * 64 + ((lg ^ (ra & 7)) << 3);
  const int offA1 = ra * 64 + (((4 + lg) ^ (ra & 7)) << 3);
  const int offB0 = rb * 64 + ((lg ^ (rb & 7)) << 3);
  const int offB1 = rb * 64 + (((4 + lg) ^ (rb & 7)) << 3);

  f4v acc[4][4];
#pragma unroll
  for (int f = 0; f < 4; ++f)
#pragma unroll
    for (int g = 0; g < 4; ++g) acc[f][g] = (f4v){0.f, 0.f, 0.f, 0.f};

  STG1(Ab, 0, Asrc);
  STG1(Bb, 0, Bsrc);
  STG1(Ab, 1, Asrc + 64);
  asm volatile("s_waitcnt vmcnt(4)" ::: "memory");
  BARRIER();

  for (int kt = 0; kt < nk; ++kt) {
    const int d = kt & 1;
    const bool p1 = (kt + 1 < nk), p2 = (kt + 2 < nk);

    s8v a[4][2], b[4][2];
#pragma unroll
    for (int f = 0; f < 4; ++f) {
      a[f][0] = *(const s8v*)(&Ab[d][offA0 + f * 1024]);
      a[f][1] = *(const s8v*)(&Ab[d][offA1 + f * 1024]);
    }
#pragma unroll
    for (int g = 0; g < 4; ++g) {
      b[g][0] = *(const s8v*)(&Bb[d][offB0 + g * 1024]);
      b[g][1] = *(const s8v*)(&Bb[d][offB1 + g * 1024]);
    }
    if (p1) STG1(Bb, d ^ 1, Bsrc + (long)(kt + 1) * 64);
    asm volatile("s_waitcnt lgkmcnt(0)" ::: "memory");   // reads retired
    BARRIER();
    if (p2) STG1(Ab, d, Asrc + (long)(kt + 2) * 64);     // A[d] slot WAR-safe

    __builtin_amdgcn_s_setprio(1);
#pragma unroll
    for (int f = 0; f < 4; ++f)
#pragma unroll
      for (int g = 0; g < 4; ++g) {
        f4v t = acc[f][g];
        t = __builtin_amdgcn_mfma_f32_16x16x32_bf16(a[f][0], b[g][0], t, 0, 0, 0);
        t = __builtin_amdgcn_mfma_f32_16x16x32_bf16(a[f][1], b[g][1], t, 0, 0, 0);
        acc[f][g] = t;
      }
    __builtin_amdgcn_s_setprio(0);

    if (p2) asm volatile("s_waitcnt vmcnt(4)" ::: "memory");
    else    asm volatile("s_waitcnt vmcnt(0)" ::: "memory");
    BARRIER();
  }

#pragma unroll
  for (int f = 0; f < 4; ++f) {
    long row = m0 + wm * 64 + f * 16 + lg * 4;
#pragma unroll
    for (int g = 0; g < 4; ++g) {
      long col = n0 + wn * 64 + g * 16 + lr;
      f4v v = acc[f][g];
#pragma unroll
      for (int r = 0; r < 4; ++r) C[(row + r) * ldc + col] = v[r];
    }
  }
#undef STG1
}

// ---------------------------------------------------------------------------
// Per-head RMSNorm (D=128) + RoPE for K HEADS ONLY, in-place, vectorized.
// ---------------------------------------------------------------------------
__global__ __launch_bounds__(256) void rms_rope_k(us* __restrict__ qkv,
                                                  const float* __restrict__ fc,
                                                  const float* __restrict__ kw) {
  int idx = blockIdx.x * 4 + (threadIdx.x >> 6);
  int lane = threadIdx.x & 63;
  int head = idx & 7;                  // 8 K heads
  int row = idx >> 3;                  // b*1024 + s
  int s = row & 1023;
  us* p = qkv + (long)row * 6144 + 4096 + head * 128;

  unsigned v = ((const unsigned*)p)[lane];
  float x0 = b2f((us)(v & 0xffff)), x1 = b2f((us)(v >> 16));
  float ss = x0 * x0 + x1 * x1;
#pragma unroll
  for (int off = 32; off; off >>= 1) ss += __shfl_xor(ss, off);
  float r = rsqrtf(ss * (1.0f / 128.0f) + 1e-6f);
  float2v wv = ((const float2v*)kw)[lane];
  float y0 = x0 * r * wv[0], y1 = x1 * r * wv[1];
  float py0 = __shfl(y0, lane ^ 32);
  float py1 = __shfl(y1, lane ^ 32);
  float2v cv = ((const float2v*)(fc + (long)s * 128))[lane];
  const float* sbase = (lane < 32) ? (fc + 2 * 1024 * 128) : (fc + 1024 * 128);
  float2v sv = ((const float2v*)(sbase + (long)s * 128))[lane];
  float e0 = y0 * cv[0] + py0 * sv[0];
  float e1 = y1 * cv[1] + py1 * sv[1];
  ((unsigned*)p)[lane] = (unsigned)f2b(e0) | ((unsigned)f2b(e1) << 16);
}

// ---------------------------------------------------------------------------
// Flash attention (no mask), GQA 4:1. Block = 8 waves = 128 q-rows; 64-key
// tiles. Q RMSNorm+RoPE fused in the prologue. T13 defer-max (THR=8).
// ---------------------------------------------------------------------------
__global__ __launch_bounds__(512) void attn_k(const us* __restrict__ qkv,
                                              us* __restrict__ ao,
                                              const float* __restrict__ fc,
                                              const float* __restrict__ qw) {
  __shared__ us Kt[64 * 128];   // [key][d], rows 256B, XOR-swizzled
  __shared__ us Vt[128 * 72];   // [d][key], padded rows (144B)
  __shared__ us Pl[8 * 1024];   // per-wave 16x64 P, XOR-swizzled

  const int bid = blockIdx.x;
  const int qt = bid & 7;
  const int h = (bid >> 3) & 31;
  const int b = bid >> 8;
  const int kvh = h >> 2;
  const int tid = threadIdx.x, lane = tid & 63, w = tid >> 6;
  const int lr = lane & 15, lg = lane >> 4;

  const int srow = qt * 128 + w * 16 + lr;
  const us* Qb = qkv + (long)(b * 1024 + srow) * 6144 + h * 128;
  s8v qr[4];
#pragma unroll
  for (int ks = 0; ks < 4; ++ks) qr[ks] = *(const s8v*)(Qb + ks * 32 + lg * 8);

  float ssq = 0.f;
#pragma unroll
  for (int ks = 0; ks < 4; ++ks)
#pragma unroll
    for (int j = 0; j < 8; ++j) {
      float x = b2f((us)qr[ks][j]);
      ssq += x * x;
    }
  ssq += __shfl_xor(ssq, 16);
  ssq += __shfl_xor(ssq, 32);
  const float rr = rsqrtf(ssq * (1.0f / 128.0f) + 1e-6f);

  const float* cosp = fc + (long)srow * 128;
  const float* sinp = fc + 1024 * 128 + (long)srow * 128;
  s8v qf[4];
#pragma unroll
  for (int ks = 0; ks < 4; ++ks) {
    const int d0 = ks * 32 + lg * 8;
    const int dp = d0 ^ 64;
    const float sgn = (ks < 2) ? -1.f : 1.f;
#pragma unroll
    for (int j = 0; j < 8; ++j) {
      float y  = b2f((us)qr[ks][j])     * rr * qw[d0 + j];
      float yp = b2f((us)qr[ks ^ 2][j]) * rr * qw[dp + j];
      float e = y * cosp[d0 + j] + yp * sgn * sinp[d0 + j];
      qf[ks][j] = (short)f2b(e);
    }
  }

  f4v o[8];
#pragma unroll
  for (int n = 0; n < 8; ++n) o[n] = (f4v){0.f, 0.f, 0.f, 0.f};
  float m[4], l[4];
#pragma unroll
  for (int r = 0; r < 4; ++r) { m[r] = -1e30f; l[r] = 0.f; }

  const float SL = 0.08838834764831845f * 1.4426950408889634f;  // D^-1/2 * log2e
  const long krow = (long)b * 1024 * 6144 + 4096 + kvh * 128;
  const long vrow = (long)b * 1024 * 6144 + 5120 + kvh * 128;

  for (int kt = 0; kt < 16; ++kt) {
    __syncthreads();
#pragma unroll
    for (int t = 0; t < 2; ++t) {
      int c = t * 512 + tid;
      int row = c >> 4;
      int sc = (c & 15) ^ (row & 7);
      gload16(qkv + krow + (long)(kt * 64 + row) * 6144 + sc * 8, &Kt[c * 8]);
    }
    {
      int c = tid;
      int kp = c & 31;
      int d0 = (c >> 5) * 8;
      const us* vsrc = qkv + vrow + (long)(kt * 64) * 6144 + d0;
      s8v va = *(const s8v*)(vsrc + (long)(2 * kp) * 6144);
      s8v vb = *(const s8v*)(vsrc + (long)(2 * kp + 1) * 6144);
#pragma unroll
      for (int i = 0; i < 8; ++i) {
        unsigned pk = (unsigned)(us)va[i] | ((unsigned)(us)vb[i] << 16);
        *(unsigned*)&Vt[(d0 + i) * 72 + 2 * kp] = pk;
      }
    }
    __syncthreads();

    f4v sacc[4];
#pragma unroll
    for (int j = 0; j < 4; ++j) sacc[j] = (f4v){0.f, 0.f, 0.f, 0.f};
    __builtin_amdgcn_s_setprio(1);
#pragma unroll
    for (int ks = 0; ks < 4; ++ks) {
#pragma unroll
      for (int j = 0; j < 4; ++j) {
        int key = j * 16 + lr;
        s8v kf = *(const s8v*)&Kt[key * 128 + (((ks * 64 + lg * 16) ^ ((key & 7) << 4)) >> 1)];
        sacc[j] = __builtin_amdgcn_mfma_f32_16x16x32_bf16(qf[ks], kf, sacc[j], 0, 0, 0);
      }
    }
    __builtin_amdgcn_s_setprio(0);

    float sm[4];
#pragma unroll
    for (int r = 0; r < 4; ++r)
      sm[r] = fmaxf(fmaxf(sacc[0][r], sacc[1][r]), fmaxf(sacc[2][r], sacc[3][r]));
#pragma unroll
    for (int off = 1; off < 16; off <<= 1)
#pragma unroll
      for (int r = 0; r < 4; ++r) sm[r] = fmaxf(sm[r], __shfl_xor(sm[r], off));
    bool ok = true;
#pragma unroll
    for (int r = 0; r < 4; ++r) ok = ok && (sm[r] * SL <= m[r] + 8.f);
    if (!__all(ok)) {
#pragma unroll
      for (int r = 0; r < 4; ++r) {
        float nm = fmaxf(m[r], sm[r] * SL);
        float alpha = exp2f(m[r] - nm);
        m[r] = nm;
        l[r] *= alpha;
#pragma unroll
        for (int n = 0; n < 8; ++n) o[n][r] *= alpha;
      }
    }

    us* pw = Pl + w * 1024;
#pragma unroll
    for (int j = 0; j < 4; ++j)
#pragma unroll
      for (int r = 0; r < 4; ++r) {
        float p = exp2f(sacc[j][r] * SL - m[r]);
        l[r] += p;
        int prow = lg * 4 + r, pcol = j * 16 + lr;
        pw[(prow * 128 + ((pcol * 2) ^ ((prow & 7) << 4))) >> 1] = f2b(p);
      }

    __builtin_amdgcn_s_setprio(1);
#pragma unroll
    for (int ks = 0; ks < 2; ++ks) {
      int bo = ks * 64 + lg * 16;
      s8v pf = *(const s8v*)&Pl[w * 1024 + ((lr * 128 + (bo ^ ((lr & 7) << 4))) >> 1)];
#pragma unroll
      for (int n = 0; n < 8; ++n) {
        s8v vf = *(const s8v*)&Vt[(n * 16 + lr) * 72 + ks * 32 + lg * 8];
        o[n] = __builtin_amdgcn_mfma_f32_16x16x32_bf16(pf, vf, o[n], 0, 0, 0);
      }
    }
    __builtin_amdgcn_s_setprio(0);
  }

#pragma unroll
  for (int off = 1; off < 16; off <<= 1)
#pragma unroll
    for (int r = 0; r < 4; ++r) l[r] += __shfl_xor(l[r], off);
  float inv[4];
#pragma unroll
  for (int r = 0; r < 4; ++r) inv[r] = 1.f / l[r];
  const long ob = (long)(b * 1024 + qt * 128 + w * 16) * 4096 + h * 128;
#pragma unroll
  for (int n = 0; n < 8; ++n)
#pragma unroll
    for (int r = 0; r < 4; ++r)
      ao[ob + (long)(lg * 4 + r) * 4096 + n * 16 + lr] = f2b(o[n][r] * inv[r]);
}

// ---------------------------------------------------------------------------
// Launch
// ---------------------------------------------------------------------------
extern "C" void kernel_launch(void* const* d_in, const int* in_sizes, int n_in,
                              void* d_out, int out_size, void* d_ws, size_t ws_size,
                              hipStream_t stream) {
  const float* hidden = (const float*)d_in[0];
  const float* fc     = (const float*)d_in[1];
  const float* Wq     = (const float*)d_in[2];
  const float* Wk     = (const float*)d_in[3];
  const float* Wv     = (const float*)d_in[4];
  const float* Wo     = (const float*)d_in[5];
  const float* qw     = (const float*)d_in[6];
  const float* kw     = (const float*)d_in[7];

  us* hb  = (us*)d_ws;                          // [2048][4096] bf16
  us* wb  = hb + (long)2048 * 4096;             // [10240][4096] bf16 (Wq|Wk|Wv|Wo)
  us* wbo = wb + (long)6144 * 4096;             // Wo bf16 [4096][4096]
  us* qkv = wbo + (long)4096 * 4096;            // [2048][6144] bf16
  us* ao  = qkv + (long)2048 * 6144;            // [2048][4096] bf16

  // convert hidden|Wq|Wk|Wv -> contiguous bf16 at hb (Wo converted in-gemm)
  cvt_all_k<<<16384, 256, 0, stream>>>(hidden, Wq, Wk, Wv, hb);

  // fused QKV projection (192 gemm blocks) + Wo convert (64 tail blocks)
  gemm8p<128, false, true><<<256, 512, 0, stream>>>(
      hb, wb, qkv, 4096, 64, 6144, 4, 6, 4, 192, Wo, wbo);

  // K-head RMSNorm + RoPE in place (Q handled inside attn)
  rms_rope_k<<<4096, 256, 0, stream>>>(qkv, fc, kw);

  // flash attention (Q rms+rope fused, 128 q-rows/block) -> bf16 [2048][4096]
  attn_k<<<512, 512, 0, stream>>>(qkv, ao, fc, qw);

  // output projection: 128x128 tiles, 512 blocks (2 blocks/CU), 1 pair/K-tile
  gemm2p128<<<512, 256, 0, stream>>>(ao, wbo, (float*)d_out);
}